// Round 8
// baseline (80.352 us; speedup 1.0000x reference)
//
#include <hip/hip_runtime.h>
#include <hip/hip_bf16.h>
#include <math.h>

#define XT_BSTRIDE (66*66*256)
#define THETA_ 0.7f

typedef unsigned short u16;
typedef __attribute__((ext_vector_type(8))) short bf16x8;
typedef __attribute__((ext_vector_type(4))) float f32x4;

#define GLOAD16(gp, lp) __builtin_amdgcn_global_load_lds( \
    (const __attribute__((address_space(1))) unsigned int*)(gp), \
    (__attribute__((address_space(3))) unsigned int*)(lp), 16, 0, 0)

__device__ __forceinline__ float bf2f(u16 v) {
  union { unsigned u; float f; } x; x.u = ((unsigned)v) << 16; return x.f;
}
__device__ __forceinline__ u16 f2bf(float f) {
  __hip_bfloat16 h = __float2bfloat16(f);
  return *(u16*)&h;
}

// swizzled element index within a [rows][K] bf16 matrix: per 64-k tile, the
// 8-element chunks are XOR-permuted by (row&7) so that linear global_load_lds
// lands them at XOR-swizzled LDS slots (conflict-free ds_read_b128 later).
__device__ __forceinline__ size_t swz_idx(int row, int k, int KT) {
  int kt = k >> 6, kc = (k >> 3) & 7, kj = k & 7;
  return (size_t)row * KT + kt * 64 + ((kc ^ (row & 7)) << 3) + kj;
}

// ---------------- prep: zero border + pad/transpose + weight prepack --------
__global__ __launch_bounds__(256) void prep(
    const float* __restrict__ x, const float* __restrict__ p_w,
    const float* __restrict__ m_w, const float* __restrict__ dconv_w,
    const float* __restrict__ cdc_w, u16* __restrict__ xTb,
    u16* __restrict__ W1t, u16* __restrict__ Wdt, u16* __restrict__ Wct) {
  int blk = blockIdx.x;
  if (blk < 512) {
    // pad_transpose: b(2) * h(64) * cg(4)
    int cg = blk & 3;
    int h  = (blk >> 2) & 63;
    int b  = blk >> 8;
    __shared__ float tile[64][65];
    const float* xp = x + ((size_t)(b * 256 + cg * 64)) * 4096 + h * 64;
#pragma unroll
    for (int j = 0; j < 16; j++) {
      int idx = j * 256 + threadIdx.x;
      int ci = idx >> 6, w = idx & 63;
      tile[ci][w] = xp[(size_t)ci * 4096 + w];
    }
    __syncthreads();
    u16* xo = xTb + (size_t)b * XT_BSTRIDE + ((h + 1) * 66 + 1) * 256 + cg * 64;
#pragma unroll
    for (int j = 0; j < 16; j++) {
      int idx = j * 256 + threadIdx.x;
      int w = idx >> 6, ci = idx & 63;
      xo[(size_t)w * 256 + ci] = f2bf(tile[ci][w]);
    }
    return;
  }
  if (blk < 1032) {
    // zero the 1-px padding border: 2 * 260 * 256 = 133120
    int i = (blk - 512) * 256 + threadIdx.x;
    if (i >= 133120) return;
    int c = i & 255;
    int j = i >> 8;
    int b = (j >= 260) ? 1 : 0;
    int r = j - b * 260;
    int hp, wp;
    if (r < 66)       { hp = 0;        wp = r; }
    else if (r < 132) { hp = 65;       wp = r - 66; }
    else if (r < 196) { hp = r - 131;  wp = 0; }
    else              { hp = r - 195;  wp = 65; }
    xTb[(size_t)b * XT_BSTRIDE + (hp * 66 + wp) * 256 + c] = 0;
    return;
  }
  // prepack weights (bf16, B^T, swizzled); 991232 items
  int i = (blk - 1032) * 256 + threadIdx.x;
  if (i < 73728) {
    int o = i / 2304, k = i % 2304;
    int kp = k >> 8, c = k & 255;
    float v = 0.f;
    if (o < 18)      v = p_w[((size_t)o * 256 + c) * 9 + kp];
    else if (o < 27) v = m_w[((size_t)(o - 18) * 256 + c) * 9 + kp];
    W1t[swz_idx(o, k, 2304)] = f2bf(v);
    return;
  }
  int j = i - 73728;
  if (j < 589824) {
    int o = j / 2304, k = j % 2304;
    int n = k >> 8, c = k & 255;
    Wdt[swz_idx(o, k, 2304)] = f2bf(dconv_w[((size_t)o * 256 + c) * 9 + n]);
    return;
  }
  int j2 = j - 589824;
  if (j2 < 327680) {
    int o = j2 / 1280, k = j2 % 1280;
    int t = k >> 8, c = k & 255;
    const float* cw = cdc_w + ((size_t)o * 256 + c) * 5;
    float v = cw[t];
    if (t == 2) v -= THETA_ * (cw[0] + cw[1] + cw[2] + cw[3] + cw[4]);
    Wct[swz_idx(o, k, 1280)] = f2bf(v);
  }
}

// ---------------- sampling params (sums split-K partials, adds bias) --------
__global__ __launch_bounds__(256) void sample_params(
    const float* __restrict__ omp, const float* __restrict__ p_b,
    const float* __restrict__ m_b, int4* __restrict__ sidx,
    float4* __restrict__ sg) {
  int i = blockIdx.x * 256 + threadIdx.x;
  if (i >= 73728) return;
  int n = i % 9;
  int p = i / 9;
  int b = p >> 12;
  int hw = p & 4095;
  int h = hw >> 6, w = hw & 63;
  float offx = p_b[n], offy = p_b[9 + n], mraw = m_b[n];
#pragma unroll
  for (int ks = 0; ks < 4; ks++) {
    const float* base = omp + ks * 221184 + b * 110592;
    offx += base[(size_t)n * 4096 + hw];
    offy += base[(size_t)(9 + n) * 4096 + hw];
    mraw += base[(size_t)(18 + n) * 4096 + hw];
  }
  float px = offx + (float)(h + n / 3);
  float py = offy + (float)(w + n % 3);
  float fx = floorf(px), fy = floorf(py);
  float qx0 = fminf(fmaxf(fx, 0.f), 65.f);
  float qy0 = fminf(fmaxf(fy, 0.f), 65.f);
  float qx1 = fminf(fmaxf(fx + 1.f, 0.f), 65.f);
  float qy1 = fminf(fmaxf(fy + 1.f, 0.f), 65.f);
  float pxc = fminf(fmaxf(px, 0.f), 65.f);
  float pyc = fminf(fmaxf(py, 0.f), 65.f);
  float gx0 = 1.f + (qx0 - pxc);
  float gx1 = 1.f - (qx1 - pxc);
  float gy0 = 1.f + (qy0 - pyc);
  float gy1 = 1.f - (qy1 - pyc);
  float m = 1.f / (1.f + expf(-mraw));
  sidx[i] = make_int4((int)qx0 * 66 + (int)qy0, (int)qx1 * 66 + (int)qy1,
                      (int)qx0 * 66 + (int)qy1, (int)qx1 * 66 + (int)qy0);
  sg[i] = make_float4(gx0 * gy0 * m, gx1 * gy1 * m, gx0 * gy1 * m, gx1 * gy0 * m);
}

// ---------------- offmod partial GEMM (BM=128, BN=32, virtual 9-tap A) ------
__device__ __forceinline__ void offmod_body(
    const u16* __restrict__ xTb, const u16* __restrict__ Bt,
    float* __restrict__ outp, int mt, int kt0, int nkt, u16* As, u16* Bs) {
  int tid = threadIdx.x;
  int wid = tid >> 6, lane = tid & 63;
  int pbase = mt * 128;
  int l8 = lane >> 3, l7 = lane & 7;
  int lr = lane & 15, lg = lane >> 4;

  f32x4 acc[2][2];
#pragma unroll
  for (int i = 0; i < 2; i++)
#pragma unroll
    for (int j = 0; j < 2; j++) acc[i][j] = {0.f, 0.f, 0.f, 0.f};

  auto stage = [&](int kt, u16* Ah, u16* Bh) {
    int t = kt >> 2, c0 = (kt & 3) << 6;
    int dh = t / 3, dw = t % 3;
#pragma unroll
    for (int i = 0; i < 4; i++) {
      int r0 = wid * 32 + i * 8;
      int r = r0 + l8;
      int p = pbase + r;
      int b = p >> 12, hw = p & 4095, h = hw >> 6, w = hw & 63;
      int chunk = l7 ^ (r & 7);
      const u16* g = xTb + (size_t)b * XT_BSTRIDE +
                     ((h + dh) * 66 + (w + dw)) * 256 + c0 + (chunk << 3);
      GLOAD16(g, &Ah[r0 * 64]);
    }
    {
      int o0 = wid * 8;
      const u16* g = Bt + (size_t)(o0 + l8) * 2304 + kt * 64 + (l7 << 3);
      GLOAD16(g, &Bh[o0 * 64]);
    }
  };

  stage(kt0, As, Bs);
  __syncthreads();

  for (int it = 0; it < nkt; it++) {
    int cur = it & 1;
    u16* Ac = As + cur * (128 * 64);
    u16* Bc = Bs + cur * (32 * 64);
    if (it + 1 < nkt)
      stage(kt0 + it + 1, As + (cur ^ 1) * (128 * 64), Bs + (cur ^ 1) * (32 * 64));

    bf16x8 av[2][2], bv[2][2];
#pragma unroll
    for (int mf = 0; mf < 2; mf++) {
      int r = wid * 32 + mf * 16 + lr;
#pragma unroll
      for (int ks = 0; ks < 2; ks++) {
        int kc = ks * 4 + lg;
        av[mf][ks] = *(const bf16x8*)&Ac[r * 64 + ((kc ^ (r & 7)) << 3)];
      }
    }
#pragma unroll
    for (int nf = 0; nf < 2; nf++) {
      int o = nf * 16 + lr;
#pragma unroll
      for (int ks = 0; ks < 2; ks++) {
        int kc = ks * 4 + lg;
        bv[nf][ks] = *(const bf16x8*)&Bc[o * 64 + ((kc ^ (o & 7)) << 3)];
      }
    }
#pragma unroll
    for (int nf = 0; nf < 2; nf++)
#pragma unroll
      for (int mf = 0; mf < 2; mf++)
#pragma unroll
        for (int ks = 0; ks < 2; ks++)
          acc[nf][mf] = __builtin_amdgcn_mfma_f32_16x16x32_bf16(
              bv[nf][ks], av[mf][ks], acc[nf][mf], 0, 0, 0);
    __syncthreads();
  }

#pragma unroll
  for (int nf = 0; nf < 2; nf++)
#pragma unroll
    for (int mf = 0; mf < 2; mf++) {
      int p = pbase + wid * 32 + mf * 16 + lr;
      int hw = p & 4095, b = p >> 12;
      int o0 = nf * 16 + lg * 4;
      f32x4 v = acc[nf][mf];
#pragma unroll
      for (int e = 0; e < 4; e++) {
        int o = o0 + e;
        if (o < 27)
          outp[(size_t)(b * 27 + o) * 4096 + hw] = v[e];
      }
    }
}

__global__ __launch_bounds__(256) void gemm_offmod(const u16* __restrict__ xTb,
                                                   const u16* __restrict__ W1t,
                                                   float* __restrict__ omp) {
  __shared__ u16 As[2 * 128 * 64];
  __shared__ u16 Bs[2 * 32 * 64];
  int bid = blockIdx.x;
  int xcd = bid & 7;
  int i = bid >> 3;                 // 0..31
  int mt = xcd * 8 + (i & 7);
  int ks = i >> 3;                  // 0..3
  offmod_body(xTb, W1t, omp + ks * 221184, mt, ks * 9, 9, As, Bs);
}

// ---------------- fused deform GEMM (BM=64, BN=256, gather into LDS) --------
// Each block owns 64 pixels x ALL 256 out-channels; the bilinear-gathered,
// modulated A-tile is built in registers from L2-resident xTb and ds_written
// (XOR-swizzled) into LDS, double-buffered against the MFMA of the current
// tile. Zero gather redundancy (nt=1).
// LDS layout in S (u16 units): A halves [0,4096),[4096,8192);
//                              B halves [8192,24576),[24576,40960)
__device__ void deform_body(const u16* __restrict__ xTb,
                            const u16* __restrict__ Wdt,
                            const int4* __restrict__ sidx,
                            const float4* __restrict__ sg,
                            float* __restrict__ out, int mt, u16* S) {
  const int NKT = 36;
  int tid = threadIdx.x;
  int wid = tid >> 6, lane = tid & 63;
  int l8 = lane >> 3, l7 = lane & 7;
  int lr = lane & 15, lg = lane >> 4;
  int pbase = mt * 64;
  int b = pbase >> 12;
  const u16* xb = xTb + (size_t)b * XT_BSTRIDE;

  // gather assignment: row gr = tid>>2 (0..63), chunk pair kc0 = (tid&3)*2
  int gr = tid >> 2;
  int gp = pbase + gr;
  int kc0 = (tid & 3) * 2;

  f32x4 acc[4][4];  // [nf][mf]
#pragma unroll
  for (int i = 0; i < 4; i++)
#pragma unroll
    for (int j = 0; j < 4; j++) acc[i][j] = {0.f, 0.f, 0.f, 0.f};

  u16* A0 = S;
  u16* B0 = S + 8192;

  bf16x8 p0, p1;
  auto gatherA = [&](int kt) {
    int tap = kt >> 2, c0 = (kt & 3) << 6;
    int s = gp * 9 + tap;
    int4 qi = sidx[s];
    float4 g = sg[s];
    const u16* xc = xb + c0 + (kc0 << 3);
    bf16x8 a0 = *(const bf16x8*)(xc + (size_t)qi.x * 256);
    bf16x8 a1 = *(const bf16x8*)(xc + (size_t)qi.y * 256);
    bf16x8 a2 = *(const bf16x8*)(xc + (size_t)qi.z * 256);
    bf16x8 a3 = *(const bf16x8*)(xc + (size_t)qi.w * 256);
    bf16x8 b0 = *(const bf16x8*)(xc + 8 + (size_t)qi.x * 256);
    bf16x8 b1 = *(const bf16x8*)(xc + 8 + (size_t)qi.y * 256);
    bf16x8 b2 = *(const bf16x8*)(xc + 8 + (size_t)qi.z * 256);
    bf16x8 b3 = *(const bf16x8*)(xc + 8 + (size_t)qi.w * 256);
#pragma unroll
    for (int j = 0; j < 8; j++) {
      float v0 = g.x * bf2f((u16)a0[j]) + g.y * bf2f((u16)a1[j]) +
                 g.z * bf2f((u16)a2[j]) + g.w * bf2f((u16)a3[j]);
      float v1 = g.x * bf2f((u16)b0[j]) + g.y * bf2f((u16)b1[j]) +
                 g.z * bf2f((u16)b2[j]) + g.w * bf2f((u16)b3[j]);
      p0[j] = (short)f2bf(v0);
      p1[j] = (short)f2bf(v1);
    }
  };
  auto writeA = [&](u16* Ah) {
    *(bf16x8*)&Ah[gr * 64 + ((kc0 ^ (gr & 7)) << 3)] = p0;
    *(bf16x8*)&Ah[gr * 64 + (((kc0 + 1) ^ (gr & 7)) << 3)] = p1;
  };
  auto stageB = [&](int kt, u16* Bh) {
#pragma unroll
    for (int i = 0; i < 8; i++) {
      int o0 = wid * 64 + i * 8;
      const u16* g = Wdt + (size_t)(o0 + l8) * 2304 + kt * 64 + (l7 << 3);
      GLOAD16(g, &Bh[o0 * 64]);
    }
  };

  // prologue
  gatherA(0);
  writeA(A0);
  stageB(0, B0);
  __syncthreads();

  for (int it = 0; it < NKT; it++) {
    int cur = it & 1;
    u16* Ac = A0 + cur * 4096;
    u16* Bc = B0 + cur * 16384;
    // issue next tile's gather loads + bilinear early (latency hides under
    // the ds_read + MFMA below; compiler sinks the waitcnt to first use)
    if (it + 1 < NKT) gatherA(it + 1);

    bf16x8 av[4][2], bv[4][2];
#pragma unroll
    for (int mf = 0; mf < 4; mf++) {
      int r = mf * 16 + lr;
#pragma unroll
      for (int ks = 0; ks < 2; ks++) {
        int kc = ks * 4 + lg;
        av[mf][ks] = *(const bf16x8*)&Ac[r * 64 + ((kc ^ (r & 7)) << 3)];
      }
    }
#pragma unroll
    for (int nf = 0; nf < 4; nf++) {
      int o = wid * 64 + nf * 16 + lr;
#pragma unroll
      for (int ks = 0; ks < 2; ks++) {
        int kc = ks * 4 + lg;
        bv[nf][ks] = *(const bf16x8*)&Bc[o * 64 + ((kc ^ (o & 7)) << 3)];
      }
    }
#pragma unroll
    for (int nf = 0; nf < 4; nf++)
#pragma unroll
      for (int mf = 0; mf < 4; mf++)
#pragma unroll
        for (int ks = 0; ks < 2; ks++)
          acc[nf][mf] = __builtin_amdgcn_mfma_f32_16x16x32_bf16(
              bv[nf][ks], av[mf][ks], acc[nf][mf], 0, 0, 0);

    if (it + 1 < NKT) {
      writeA(A0 + (cur ^ 1) * 4096);
      stageB(it + 1, B0 + (cur ^ 1) * 16384);
    }
    __syncthreads();
  }

  // epilogue: ReLU, out ch 0..255
#pragma unroll
  for (int nf = 0; nf < 4; nf++)
#pragma unroll
    for (int mf = 0; mf < 4; mf++) {
      int p = pbase + mf * 16 + lr;
      int hw = p & 4095;
      int og = wid * 64 + nf * 16 + lg * 4;
      f32x4 v = acc[nf][mf];
#pragma unroll
      for (int e = 0; e < 4; e++)
        out[(size_t)(b * 512 + og + e) * 4096 + hw] = fmaxf(v[e], 0.f);
    }
}

// ---------------- cdc GEMM (BM=64, BN=64, virtual 5-tap A) ------------------
// LDS in S: A halves [0,4096),[4096,8192); B halves [8192,12288),[12288,16384)
__device__ void cdc_body(const u16* __restrict__ xTb,
                         const u16* __restrict__ Wct,
                         float* __restrict__ out, int mt, int nt, u16* S) {
  const int NKT = 20;
  int tid = threadIdx.x;
  int wid = tid >> 6, lane = tid & 63;
  int wr = wid >> 1, wc = wid & 1;
  int l8 = lane >> 3, l7 = lane & 7;
  int lr = lane & 15, lg = lane >> 4;
  int pbase = mt * 64;
  int obase = nt * 64;
  int b = pbase >> 12;

  f32x4 acc[2][2];
#pragma unroll
  for (int i = 0; i < 2; i++)
#pragma unroll
    for (int j = 0; j < 2; j++) acc[i][j] = {0.f, 0.f, 0.f, 0.f};

  const int dh1[5] = {0, 1, 1, 1, 2}, dw1[5] = {1, 0, 1, 2, 1};
  u16* A0 = S;
  u16* B0 = S + 8192;

  auto stage = [&](int kt, u16* Ah, u16* Bh) {
    int t = kt >> 2, c0 = (kt & 3) << 6;
    int dh = dh1[t], dw = dw1[t];
#pragma unroll
    for (int i = 0; i < 2; i++) {
      int r0 = wid * 16 + i * 8;
      int r = r0 + l8;
      int p = pbase + r;
      int hw = p & 4095, h = hw >> 6, w = hw & 63;
      int chunk = l7 ^ (r & 7);
      const u16* g = xTb + (size_t)b * XT_BSTRIDE +
                     ((h + dh) * 66 + (w + dw)) * 256 + c0 + (chunk << 3);
      GLOAD16(g, &Ah[r0 * 64]);
    }
#pragma unroll
    for (int i = 0; i < 2; i++) {
      int o0 = wid * 16 + i * 8;
      const u16* g = Wct + (size_t)(obase + o0 + l8) * 1280 + kt * 64 + (l7 << 3);
      GLOAD16(g, &Bh[o0 * 64]);
    }
  };

  stage(0, A0, B0);
  __syncthreads();

  for (int it = 0; it < NKT; it++) {
    int cur = it & 1;
    u16* Ac = A0 + cur * 4096;
    u16* Bc = B0 + cur * 4096;
    if (it + 1 < NKT)
      stage(it + 1, A0 + (cur ^ 1) * 4096, B0 + (cur ^ 1) * 4096);

    bf16x8 av[2][2], bv[2][2];
#pragma unroll
    for (int mf = 0; mf < 2; mf++) {
      int r = wr * 32 + mf * 16 + lr;
#pragma unroll
      for (int ks = 0; ks < 2; ks++) {
        int kc = ks * 4 + lg;
        av[mf][ks] = *(const bf16x8*)&Ac[r * 64 + ((kc ^ (r & 7)) << 3)];
      }
    }
#pragma unroll
    for (int nf = 0; nf < 2; nf++) {
      int o = wc * 32 + nf * 16 + lr;
#pragma unroll
      for (int ks = 0; ks < 2; ks++) {
        int kc = ks * 4 + lg;
        bv[nf][ks] = *(const bf16x8*)&Bc[o * 64 + ((kc ^ (o & 7)) << 3)];
      }
    }
#pragma unroll
    for (int nf = 0; nf < 2; nf++)
#pragma unroll
      for (int mf = 0; mf < 2; mf++)
#pragma unroll
        for (int ks = 0; ks < 2; ks++)
          acc[nf][mf] = __builtin_amdgcn_mfma_f32_16x16x32_bf16(
              bv[nf][ks], av[mf][ks], acc[nf][mf], 0, 0, 0);
    __syncthreads();
  }

#pragma unroll
  for (int nf = 0; nf < 2; nf++)
#pragma unroll
    for (int mf = 0; mf < 2; mf++) {
      int p = pbase + wr * 32 + mf * 16 + lr;
      int hw = p & 4095;
      int og = 256 + obase + wc * 32 + nf * 16 + lg * 4;
      f32x4 v = acc[nf][mf];
#pragma unroll
      for (int e = 0; e < 4; e++)
        out[(size_t)(b * 512 + og + e) * 4096 + hw] = fmaxf(v[e], 0.f);
    }
}

// ---------------- main GEMM: 128 fused-deform blocks + 512 cdc blocks -------
__global__ __launch_bounds__(256, 2) void gemm_main(
    const u16* __restrict__ xTb, const u16* __restrict__ Wdt,
    const u16* __restrict__ Wct, const int4* __restrict__ sidx,
    const float4* __restrict__ sg, float* __restrict__ out) {
  __shared__ u16 S[40960];   // 80 KiB
  int bid = blockIdx.x;
  if (bid < 128) {
    // deform: XCD-chunked, 16 consecutive mt per XCD
    int mt = (bid & 7) * 16 + (bid >> 3);
    deform_body(xTb, Wdt, sidx, sg, out, mt, S);
  } else {
    int i = bid - 128;               // 0..511
    int xcd = i & 7;
    int j = i >> 3;                  // 0..63
    int mt = xcd * 16 + (j & 15);
    int nt = j >> 4;                 // 0..3
    cdc_body(xTb, Wct, out, mt, nt, S);
  }
}

// ---------------- launch ----------------------------------------------------
extern "C" void kernel_launch(void* const* d_in, const int* in_sizes, int n_in,
                              void* d_out, int out_size, void* d_ws, size_t ws_size,
                              hipStream_t stream) {
  (void)in_sizes; (void)n_in; (void)out_size; (void)ws_size;
  const float* x       = (const float*)d_in[0];
  const float* p_w     = (const float*)d_in[1];
  const float* p_b     = (const float*)d_in[2];
  const float* m_w     = (const float*)d_in[3];
  const float* m_b     = (const float*)d_in[4];
  const float* dconv_w = (const float*)d_in[5];
  const float* cdc_w   = (const float*)d_in[6];
  float* out = (float*)d_out;
  char* ws = (char*)d_ws;

  u16*   xTb  = (u16*)(ws);                   // 4,460,544 B
  float* omp  = (float*)(ws + 4460544);       // 3,538,944 B (4 K-slices)
  u16*   W1t  = (u16*)(ws + 7999488);         //   147,456 B
  u16*   Wdt  = (u16*)(ws + 8146944);         // 1,179,648 B
  u16*   Wct  = (u16*)(ws + 9326592);         //   655,360 B
  int4*  sidx = (int4*)(ws + 9981952);        // 1,179,648 B
  float4* sg  = (float4*)(ws + 11161600);     // 1,179,648 B (end 12,341,248)

  prep<<<4904, 256, 0, stream>>>(x, p_w, m_w, dconv_w, cdc_w, xTb, W1t, Wdt, Wct);
  gemm_offmod<<<256, 256, 0, stream>>>(xTb, W1t, omp);
  sample_params<<<288, 256, 0, stream>>>(omp, p_b, m_b, sidx, sg);
  gemm_main<<<640, 256, 0, stream>>>(xTb, Wdt, Wct, sidx, sg, out);
}

// Round 9
// 66.040 us; speedup vs baseline: 1.2167x; 1.2167x over previous
//
#include <hip/hip_runtime.h>
#include <hip/hip_bf16.h>
#include <math.h>

#define XT_BSTRIDE (66*66*256)
#define THETA_ 0.7f

typedef unsigned short u16;
typedef __attribute__((ext_vector_type(8))) short bf16x8;
typedef __attribute__((ext_vector_type(4))) float f32x4;

#define GLOAD16(gp, lp) __builtin_amdgcn_global_load_lds( \
    (const __attribute__((address_space(1))) unsigned int*)(gp), \
    (__attribute__((address_space(3))) unsigned int*)(lp), 16, 0, 0)

__device__ __forceinline__ float bf2f(u16 v) {
  union { unsigned u; float f; } x; x.u = ((unsigned)v) << 16; return x.f;
}
__device__ __forceinline__ u16 f2bf(float f) {
  __hip_bfloat16 h = __float2bfloat16(f);
  return *(u16*)&h;
}

// swizzled element index within a [rows][K] bf16 matrix: per 64-k tile, the
// 8-element chunks are XOR-permuted by (row&7) so that linear global_load_lds
// lands them at XOR-swizzled LDS slots (conflict-free ds_read_b128 later).
__device__ __forceinline__ size_t swz_idx(int row, int k, int KT) {
  int kt = k >> 6, kc = (k >> 3) & 7, kj = k & 7;
  return (size_t)row * KT + kt * 64 + ((kc ^ (row & 7)) << 3) + kj;
}

// ---------------- prep: zero border + pad/transpose + weight prepack --------
__global__ __launch_bounds__(256) void prep(
    const float* __restrict__ x, const float* __restrict__ p_w,
    const float* __restrict__ m_w, const float* __restrict__ dconv_w,
    const float* __restrict__ cdc_w, u16* __restrict__ xTb,
    u16* __restrict__ W1t, u16* __restrict__ Wdt, u16* __restrict__ Wct) {
  int blk = blockIdx.x;
  if (blk < 512) {
    // pad_transpose: b(2) * h(64) * cg(4)
    int cg = blk & 3;
    int h  = (blk >> 2) & 63;
    int b  = blk >> 8;
    __shared__ float tile[64][65];
    const float* xp = x + ((size_t)(b * 256 + cg * 64)) * 4096 + h * 64;
#pragma unroll
    for (int j = 0; j < 16; j++) {
      int idx = j * 256 + threadIdx.x;
      int ci = idx >> 6, w = idx & 63;
      tile[ci][w] = xp[(size_t)ci * 4096 + w];
    }
    __syncthreads();
    u16* xo = xTb + (size_t)b * XT_BSTRIDE + ((h + 1) * 66 + 1) * 256 + cg * 64;
#pragma unroll
    for (int j = 0; j < 16; j++) {
      int idx = j * 256 + threadIdx.x;
      int w = idx >> 6, ci = idx & 63;
      xo[(size_t)w * 256 + ci] = f2bf(tile[ci][w]);
    }
    return;
  }
  if (blk < 1032) {
    // zero the 1-px padding border: 2 * 260 * 256 = 133120
    int i = (blk - 512) * 256 + threadIdx.x;
    if (i >= 133120) return;
    int c = i & 255;
    int j = i >> 8;
    int b = (j >= 260) ? 1 : 0;
    int r = j - b * 260;
    int hp, wp;
    if (r < 66)       { hp = 0;        wp = r; }
    else if (r < 132) { hp = 65;       wp = r - 66; }
    else if (r < 196) { hp = r - 131;  wp = 0; }
    else              { hp = r - 195;  wp = 65; }
    xTb[(size_t)b * XT_BSTRIDE + (hp * 66 + wp) * 256 + c] = 0;
    return;
  }
  // prepack weights (bf16, B^T, swizzled); 991232 items
  int i = (blk - 1032) * 256 + threadIdx.x;
  if (i < 73728) {
    int o = i / 2304, k = i % 2304;
    int kp = k >> 8, c = k & 255;
    float v = 0.f;
    if (o < 18)      v = p_w[((size_t)o * 256 + c) * 9 + kp];
    else if (o < 27) v = m_w[((size_t)(o - 18) * 256 + c) * 9 + kp];
    W1t[swz_idx(o, k, 2304)] = f2bf(v);
    return;
  }
  int j = i - 73728;
  if (j < 589824) {
    int o = j / 2304, k = j % 2304;
    int n = k >> 8, c = k & 255;
    Wdt[swz_idx(o, k, 2304)] = f2bf(dconv_w[((size_t)o * 256 + c) * 9 + n]);
    return;
  }
  int j2 = j - 589824;
  if (j2 < 327680) {
    int o = j2 / 1280, k = j2 % 1280;
    int t = k >> 8, c = k & 255;
    const float* cw = cdc_w + ((size_t)o * 256 + c) * 5;
    float v = cw[t];
    if (t == 2) v -= THETA_ * (cw[0] + cw[1] + cw[2] + cw[3] + cw[4]);
    Wct[swz_idx(o, k, 1280)] = f2bf(v);
  }
}

// ---------------- sampling params (sums split-K partials, adds bias) --------
__global__ __launch_bounds__(256) void sample_params(
    const float* __restrict__ omp, const float* __restrict__ p_b,
    const float* __restrict__ m_b, int4* __restrict__ sidx,
    float4* __restrict__ sg) {
  int i = blockIdx.x * 256 + threadIdx.x;
  if (i >= 73728) return;
  int n = i % 9;
  int p = i / 9;
  int b = p >> 12;
  int hw = p & 4095;
  int h = hw >> 6, w = hw & 63;
  float offx = p_b[n], offy = p_b[9 + n], mraw = m_b[n];
#pragma unroll
  for (int ks = 0; ks < 4; ks++) {
    const float* base = omp + ks * 221184 + b * 110592;
    offx += base[(size_t)n * 4096 + hw];
    offy += base[(size_t)(9 + n) * 4096 + hw];
    mraw += base[(size_t)(18 + n) * 4096 + hw];
  }
  float px = offx + (float)(h + n / 3);
  float py = offy + (float)(w + n % 3);
  float fx = floorf(px), fy = floorf(py);
  float qx0 = fminf(fmaxf(fx, 0.f), 65.f);
  float qy0 = fminf(fmaxf(fy, 0.f), 65.f);
  float qx1 = fminf(fmaxf(fx + 1.f, 0.f), 65.f);
  float qy1 = fminf(fmaxf(fy + 1.f, 0.f), 65.f);
  float pxc = fminf(fmaxf(px, 0.f), 65.f);
  float pyc = fminf(fmaxf(py, 0.f), 65.f);
  float gx0 = 1.f + (qx0 - pxc);
  float gx1 = 1.f - (qx1 - pxc);
  float gy0 = 1.f + (qy0 - pyc);
  float gy1 = 1.f - (qy1 - pyc);
  float m = 1.f / (1.f + expf(-mraw));
  sidx[i] = make_int4((int)qx0 * 66 + (int)qy0, (int)qx1 * 66 + (int)qy1,
                      (int)qx0 * 66 + (int)qy1, (int)qx1 * 66 + (int)qy0);
  sg[i] = make_float4(gx0 * gy0 * m, gx1 * gy1 * m, gx0 * gy1 * m, gx1 * gy0 * m);
}

// ---------------- offmod partial GEMM (BM=128, BN=32, virtual 9-tap A) ------
__device__ __forceinline__ void offmod_body(
    const u16* __restrict__ xTb, const u16* __restrict__ Bt,
    float* __restrict__ outp, int mt, int kt0, int nkt, u16* As, u16* Bs) {
  int tid = threadIdx.x;
  int wid = tid >> 6, lane = tid & 63;
  int pbase = mt * 128;
  int l8 = lane >> 3, l7 = lane & 7;
  int lr = lane & 15, lg = lane >> 4;

  f32x4 acc[2][2];
#pragma unroll
  for (int i = 0; i < 2; i++)
#pragma unroll
    for (int j = 0; j < 2; j++) acc[i][j] = {0.f, 0.f, 0.f, 0.f};

  auto stage = [&](int kt, u16* Ah, u16* Bh) {
    int t = kt >> 2, c0 = (kt & 3) << 6;
    int dh = t / 3, dw = t % 3;
#pragma unroll
    for (int i = 0; i < 4; i++) {
      int r0 = wid * 32 + i * 8;
      int r = r0 + l8;
      int p = pbase + r;
      int b = p >> 12, hw = p & 4095, h = hw >> 6, w = hw & 63;
      int chunk = l7 ^ (r & 7);
      const u16* g = xTb + (size_t)b * XT_BSTRIDE +
                     ((h + dh) * 66 + (w + dw)) * 256 + c0 + (chunk << 3);
      GLOAD16(g, &Ah[r0 * 64]);
    }
    {
      int o0 = wid * 8;
      const u16* g = Bt + (size_t)(o0 + l8) * 2304 + kt * 64 + (l7 << 3);
      GLOAD16(g, &Bh[o0 * 64]);
    }
  };

  stage(kt0, As, Bs);
  __syncthreads();

  for (int it = 0; it < nkt; it++) {
    int cur = it & 1;
    u16* Ac = As + cur * (128 * 64);
    u16* Bc = Bs + cur * (32 * 64);
    if (it + 1 < nkt)
      stage(kt0 + it + 1, As + (cur ^ 1) * (128 * 64), Bs + (cur ^ 1) * (32 * 64));

    bf16x8 av[2][2], bv[2][2];
#pragma unroll
    for (int mf = 0; mf < 2; mf++) {
      int r = wid * 32 + mf * 16 + lr;
#pragma unroll
      for (int ks = 0; ks < 2; ks++) {
        int kc = ks * 4 + lg;
        av[mf][ks] = *(const bf16x8*)&Ac[r * 64 + ((kc ^ (r & 7)) << 3)];
      }
    }
#pragma unroll
    for (int nf = 0; nf < 2; nf++) {
      int o = nf * 16 + lr;
#pragma unroll
      for (int ks = 0; ks < 2; ks++) {
        int kc = ks * 4 + lg;
        bv[nf][ks] = *(const bf16x8*)&Bc[o * 64 + ((kc ^ (o & 7)) << 3)];
      }
    }
#pragma unroll
    for (int nf = 0; nf < 2; nf++)
#pragma unroll
      for (int mf = 0; mf < 2; mf++)
#pragma unroll
        for (int ks = 0; ks < 2; ks++)
          acc[nf][mf] = __builtin_amdgcn_mfma_f32_16x16x32_bf16(
              bv[nf][ks], av[mf][ks], acc[nf][mf], 0, 0, 0);
    __syncthreads();
  }

#pragma unroll
  for (int nf = 0; nf < 2; nf++)
#pragma unroll
    for (int mf = 0; mf < 2; mf++) {
      int p = pbase + wid * 32 + mf * 16 + lr;
      int hw = p & 4095, b = p >> 12;
      int o0 = nf * 16 + lg * 4;
      f32x4 v = acc[nf][mf];
#pragma unroll
      for (int e = 0; e < 4; e++) {
        int o = o0 + e;
        if (o < 27)
          outp[(size_t)(b * 27 + o) * 4096 + hw] = v[e];
      }
    }
}

__global__ __launch_bounds__(256) void gemm_offmod(const u16* __restrict__ xTb,
                                                   const u16* __restrict__ W1t,
                                                   float* __restrict__ omp) {
  __shared__ u16 As[2 * 128 * 64];
  __shared__ u16 Bs[2 * 32 * 64];
  int bid = blockIdx.x;
  int xcd = bid & 7;
  int i = bid >> 3;                 // 0..31
  int mt = xcd * 8 + (i & 7);
  int ks = i >> 3;                  // 0..3
  offmod_body(xTb, W1t, omp + ks * 221184, mt, ks * 9, 9, As, Bs);
}

// ---------------- fused deform GEMM (BM=32, BN=256, T14 gather split) -------
// Each block: 32 pixels x all 256 out-channels. Per K-tile: corner loads for
// tile it+1 issued into REGISTERS before the MFMA of tile it; bilinear
// convert + swizzled ds_write AFTER the MFMA (loads drain under compute).
// sidx/sg are constant over 4 K-tiles (one tap) and prefetched a full tap
// (4 iterations) ahead.
// LDS layout in S (u16): A halves [0,2048),[2048,4096);
//                        B halves [4096,20480),[20480,36864)
__device__ void deform_body(const u16* __restrict__ xTb,
                            const u16* __restrict__ Wdt,
                            const int4* __restrict__ sidx,
                            const float4* __restrict__ sg,
                            float* __restrict__ out, int mt, u16* S) {
  const int NKT = 36;
  int tid = threadIdx.x;
  int wid = tid >> 6, lane = tid & 63;
  int l8 = lane >> 3, l7 = lane & 7;
  int lr = lane & 15, lg = lane >> 4;
  int pbase = mt * 32;
  int b = pbase >> 12;
  const u16* xb = xTb + (size_t)b * XT_BSTRIDE;

  // gather assignment: row gr = tid>>3 (0..31), chunk kc = tid&7
  int gr = tid >> 3;
  int gp = pbase + gr;
  int kc = tid & 7;

  f32x4 acc[4][2];  // [nf][mf]
#pragma unroll
  for (int i = 0; i < 4; i++)
#pragma unroll
    for (int j = 0; j < 2; j++) acc[i][j] = {0.f, 0.f, 0.f, 0.f};

  u16* A0 = S;
  u16* B0 = S + 4096;

  // tap-state registers (tap = kt>>2); next-tap prefetched 4 iters early
  int4 qi = sidx[gp * 9 + 0];
  float4 g = sg[gp * 9 + 0];
  int4 qi_n = sidx[gp * 9 + 1];
  float4 g_n = sg[gp * 9 + 1];

  bf16x8 c0r, c1r, c2r, c3r;   // in-flight corner loads
  float4 gc;

  auto issueA = [&](int kt) {
    int c0 = (kt & 3) << 6;
    const u16* xc = xb + c0 + (kc << 3);
    c0r = *(const bf16x8*)(xc + (size_t)qi.x * 256);
    c1r = *(const bf16x8*)(xc + (size_t)qi.y * 256);
    c2r = *(const bf16x8*)(xc + (size_t)qi.z * 256);
    c3r = *(const bf16x8*)(xc + (size_t)qi.w * 256);
    gc = g;
  };
  auto writeA = [&](u16* Ah) {
    bf16x8 p;
#pragma unroll
    for (int j = 0; j < 8; j++) {
      float v = gc.x * bf2f((u16)c0r[j]) + gc.y * bf2f((u16)c1r[j]) +
                gc.z * bf2f((u16)c2r[j]) + gc.w * bf2f((u16)c3r[j]);
      p[j] = (short)f2bf(v);
    }
    *(bf16x8*)&Ah[gr * 64 + ((kc ^ (gr & 7)) << 3)] = p;
  };
  auto stageB = [&](int kt, u16* Bh) {
#pragma unroll
    for (int i = 0; i < 8; i++) {
      int o0 = wid * 64 + i * 8;
      const u16* gptr = Wdt + (size_t)(o0 + l8) * 2304 + kt * 64 + (l7 << 3);
      GLOAD16(gptr, &Bh[o0 * 64]);
    }
  };

  // prologue: tile 0
  issueA(0);
  stageB(0, B0);
  writeA(A0);
  __syncthreads();

  for (int it = 0; it < NKT; it++) {
    int cur = it & 1;
    u16* Ac = A0 + cur * 2048;
    u16* Bc = B0 + cur * 16384;

    if (it + 1 < NKT) {
      if (((it + 1) & 3) == 0) {       // next tile starts a new tap
        qi = qi_n; g = g_n;
        int tapn = ((it + 1) >> 2) + 1;
        if (tapn < 9) { qi_n = sidx[gp * 9 + tapn]; g_n = sg[gp * 9 + tapn]; }
      }
      issueA(it + 1);                  // VMEM issue only — drains under MFMA
      stageB(it + 1, B0 + (cur ^ 1) * 16384);
    }

    bf16x8 av[2][2], bv[4][2];
#pragma unroll
    for (int mf = 0; mf < 2; mf++) {
      int r = mf * 16 + lr;
#pragma unroll
      for (int ks = 0; ks < 2; ks++) {
        int kk = ks * 4 + lg;
        av[mf][ks] = *(const bf16x8*)&Ac[r * 64 + ((kk ^ (r & 7)) << 3)];
      }
    }
#pragma unroll
    for (int nf = 0; nf < 4; nf++) {
      int o = wid * 64 + nf * 16 + lr;
#pragma unroll
      for (int ks = 0; ks < 2; ks++) {
        int kk = ks * 4 + lg;
        bv[nf][ks] = *(const bf16x8*)&Bc[o * 64 + ((kk ^ (o & 7)) << 3)];
      }
    }
#pragma unroll
    for (int nf = 0; nf < 4; nf++)
#pragma unroll
      for (int mf = 0; mf < 2; mf++)
#pragma unroll
        for (int ks = 0; ks < 2; ks++)
          acc[nf][mf] = __builtin_amdgcn_mfma_f32_16x16x32_bf16(
              bv[nf][ks], av[mf][ks], acc[nf][mf], 0, 0, 0);

    if (it + 1 < NKT)
      writeA(A0 + (cur ^ 1) * 2048);   // convert + swizzled write, loads drained
    __syncthreads();
  }

  // epilogue: ReLU, out ch 0..255
#pragma unroll
  for (int nf = 0; nf < 4; nf++)
#pragma unroll
    for (int mf = 0; mf < 2; mf++) {
      int p = pbase + mf * 16 + lr;
      int hw = p & 4095;
      int og = wid * 64 + nf * 16 + lg * 4;
      f32x4 v = acc[nf][mf];
#pragma unroll
      for (int e = 0; e < 4; e++)
        out[(size_t)(b * 512 + og + e) * 4096 + hw] = fmaxf(v[e], 0.f);
    }
}

// ---------------- cdc GEMM (BM=64, BN=64, virtual 5-tap A) ------------------
// LDS in S: A halves [0,4096),[4096,8192); B halves [8192,12288),[12288,16384)
__device__ void cdc_body(const u16* __restrict__ xTb,
                         const u16* __restrict__ Wct,
                         float* __restrict__ out, int mt, int nt, u16* S) {
  const int NKT = 20;
  int tid = threadIdx.x;
  int wid = tid >> 6, lane = tid & 63;
  int wr = wid >> 1, wc = wid & 1;
  int l8 = lane >> 3, l7 = lane & 7;
  int lr = lane & 15, lg = lane >> 4;
  int pbase = mt * 64;
  int obase = nt * 64;
  int b = pbase >> 12;

  f32x4 acc[2][2];
#pragma unroll
  for (int i = 0; i < 2; i++)
#pragma unroll
    for (int j = 0; j < 2; j++) acc[i][j] = {0.f, 0.f, 0.f, 0.f};

  const int dh1[5] = {0, 1, 1, 1, 2}, dw1[5] = {1, 0, 1, 2, 1};
  u16* A0 = S;
  u16* B0 = S + 8192;

  auto stage = [&](int kt, u16* Ah, u16* Bh) {
    int t = kt >> 2, c0 = (kt & 3) << 6;
    int dh = dh1[t], dw = dw1[t];
#pragma unroll
    for (int i = 0; i < 2; i++) {
      int r0 = wid * 16 + i * 8;
      int r = r0 + l8;
      int p = pbase + r;
      int hw = p & 4095, h = hw >> 6, w = hw & 63;
      int chunk = l7 ^ (r & 7);
      const u16* g = xTb + (size_t)b * XT_BSTRIDE +
                     ((h + dh) * 66 + (w + dw)) * 256 + c0 + (chunk << 3);
      GLOAD16(g, &Ah[r0 * 64]);
    }
#pragma unroll
    for (int i = 0; i < 2; i++) {
      int o0 = wid * 16 + i * 8;
      const u16* g = Wct + (size_t)(obase + o0 + l8) * 1280 + kt * 64 + (l7 << 3);
      GLOAD16(g, &Bh[o0 * 64]);
    }
  };

  stage(0, A0, B0);
  __syncthreads();

  for (int it = 0; it < NKT; it++) {
    int cur = it & 1;
    u16* Ac = A0 + cur * 4096;
    u16* Bc = B0 + cur * 4096;
    if (it + 1 < NKT)
      stage(it + 1, A0 + (cur ^ 1) * 4096, B0 + (cur ^ 1) * 4096);

    bf16x8 av[2][2], bv[2][2];
#pragma unroll
    for (int mf = 0; mf < 2; mf++) {
      int r = wr * 32 + mf * 16 + lr;
#pragma unroll
      for (int ks = 0; ks < 2; ks++) {
        int kk = ks * 4 + lg;
        av[mf][ks] = *(const bf16x8*)&Ac[r * 64 + ((kk ^ (r & 7)) << 3)];
      }
    }
#pragma unroll
    for (int nf = 0; nf < 2; nf++) {
      int o = wc * 32 + nf * 16 + lr;
#pragma unroll
      for (int ks = 0; ks < 2; ks++) {
        int kk = ks * 4 + lg;
        bv[nf][ks] = *(const bf16x8*)&Bc[o * 64 + ((kk ^ (o & 7)) << 3)];
      }
    }
#pragma unroll
    for (int nf = 0; nf < 2; nf++)
#pragma unroll
      for (int mf = 0; mf < 2; mf++)
#pragma unroll
        for (int ks = 0; ks < 2; ks++)
          acc[nf][mf] = __builtin_amdgcn_mfma_f32_16x16x32_bf16(
              bv[nf][ks], av[mf][ks], acc[nf][mf], 0, 0, 0);
    __syncthreads();
  }

#pragma unroll
  for (int nf = 0; nf < 2; nf++)
#pragma unroll
    for (int mf = 0; mf < 2; mf++) {
      int p = pbase + wr * 32 + mf * 16 + lr;
      int hw = p & 4095;
      int og = 256 + obase + wc * 32 + nf * 16 + lg * 4;
      f32x4 v = acc[nf][mf];
#pragma unroll
      for (int e = 0; e < 4; e++)
        out[(size_t)(b * 512 + og + e) * 4096 + hw] = fmaxf(v[e], 0.f);
    }
}

// ---------------- main GEMM: 256 fused-deform blocks + 512 cdc blocks -------
__global__ __launch_bounds__(256, 2) void gemm_main(
    const u16* __restrict__ xTb, const u16* __restrict__ Wdt,
    const u16* __restrict__ Wct, const int4* __restrict__ sidx,
    const float4* __restrict__ sg, float* __restrict__ out) {
  __shared__ u16 S[36864];   // 72 KiB -> 2 blocks/CU
  int bid = blockIdx.x;
  if (bid < 256) {
    // deform: XCD-chunked, 32 consecutive mt per XCD
    int mt = (bid & 7) * 32 + (bid >> 3);
    deform_body(xTb, Wdt, sidx, sg, out, mt, S);
  } else {
    int i = bid - 256;               // 0..511
    int xcd = i & 7;
    int j = i >> 3;                  // 0..63
    int mt = xcd * 16 + (j & 15);
    int nt = j >> 4;                 // 0..3
    cdc_body(xTb, Wct, out, mt, nt, S);
  }
}

// ---------------- launch ----------------------------------------------------
extern "C" void kernel_launch(void* const* d_in, const int* in_sizes, int n_in,
                              void* d_out, int out_size, void* d_ws, size_t ws_size,
                              hipStream_t stream) {
  (void)in_sizes; (void)n_in; (void)out_size; (void)ws_size;
  const float* x       = (const float*)d_in[0];
  const float* p_w     = (const float*)d_in[1];
  const float* p_b     = (const float*)d_in[2];
  const float* m_w     = (const float*)d_in[3];
  const float* m_b     = (const float*)d_in[4];
  const float* dconv_w = (const float*)d_in[5];
  const float* cdc_w   = (const float*)d_in[6];
  float* out = (float*)d_out;
  char* ws = (char*)d_ws;

  u16*   xTb  = (u16*)(ws);                   // 4,460,544 B
  float* omp  = (float*)(ws + 4460544);       // 3,538,944 B (4 K-slices)
  u16*   W1t  = (u16*)(ws + 7999488);         //   147,456 B
  u16*   Wdt  = (u16*)(ws + 8146944);         // 1,179,648 B
  u16*   Wct  = (u16*)(ws + 9326592);         //   655,360 B
  int4*  sidx = (int4*)(ws + 9981952);        // 1,179,648 B
  float4* sg  = (float4*)(ws + 11161600);     // 1,179,648 B (end 12,341,248)

  prep<<<4904, 256, 0, stream>>>(x, p_w, m_w, dconv_w, cdc_w, xTb, W1t, Wdt, Wct);
  gemm_offmod<<<256, 256, 0, stream>>>(xTb, W1t, omp);
  sample_params<<<288, 256, 0, stream>>>(omp, p_b, m_b, sidx, sg);
  gemm_main<<<768, 256, 0, stream>>>(xTb, Wdt, Wct, sidx, sg, out);
}

// Round 10
// 63.241 us; speedup vs baseline: 1.2706x; 1.0442x over previous
//
#include <hip/hip_runtime.h>
#include <hip/hip_bf16.h>
#include <math.h>

#define XT_BSTRIDE (66*66*256)
#define THETA_ 0.7f

typedef unsigned short u16;
typedef __attribute__((ext_vector_type(8))) short bf16x8;
typedef __attribute__((ext_vector_type(4))) float f32x4;

#define GLOAD16(gp, lp) __builtin_amdgcn_global_load_lds( \
    (const __attribute__((address_space(1))) unsigned int*)(gp), \
    (__attribute__((address_space(3))) unsigned int*)(lp), 16, 0, 0)

__device__ __forceinline__ float bf2f(u16 v) {
  union { unsigned u; float f; } x; x.u = ((unsigned)v) << 16; return x.f;
}
__device__ __forceinline__ u16 f2bf(float f) {
  __hip_bfloat16 h = __float2bfloat16(f);
  return *(u16*)&h;
}

// swizzled element index within a [rows][K] bf16 matrix: per 64-k tile, the
// 8-element chunks are XOR-permuted by (row&7) so that linear global_load_lds
// lands them at XOR-swizzled LDS slots (conflict-free ds_read_b128 later).
__device__ __forceinline__ size_t swz_idx(int row, int k, int KT) {
  int kt = k >> 6, kc = (k >> 3) & 7, kj = k & 7;
  return (size_t)row * KT + kt * 64 + ((kc ^ (row & 7)) << 3) + kj;
}

// ---------------- prep: zero border + pad/transpose + weight prepack --------
__global__ __launch_bounds__(256) void prep(
    const float* __restrict__ x, const float* __restrict__ p_w,
    const float* __restrict__ m_w, const float* __restrict__ dconv_w,
    const float* __restrict__ cdc_w, u16* __restrict__ xTb,
    u16* __restrict__ W1t, u16* __restrict__ Wdt, u16* __restrict__ Wct) {
  int blk = blockIdx.x;
  if (blk < 512) {
    // pad_transpose: b(2) * h(64) * cg(4)
    int cg = blk & 3;
    int h  = (blk >> 2) & 63;
    int b  = blk >> 8;
    __shared__ float tile[64][65];
    const float* xp = x + ((size_t)(b * 256 + cg * 64)) * 4096 + h * 64;
#pragma unroll
    for (int j = 0; j < 16; j++) {
      int idx = j * 256 + threadIdx.x;
      int ci = idx >> 6, w = idx & 63;
      tile[ci][w] = xp[(size_t)ci * 4096 + w];
    }
    __syncthreads();
    u16* xo = xTb + (size_t)b * XT_BSTRIDE + ((h + 1) * 66 + 1) * 256 + cg * 64;
#pragma unroll
    for (int j = 0; j < 16; j++) {
      int idx = j * 256 + threadIdx.x;
      int w = idx >> 6, ci = idx & 63;
      xo[(size_t)w * 256 + ci] = f2bf(tile[ci][w]);
    }
    return;
  }
  if (blk < 1032) {
    // zero the 1-px padding border: 2 * 260 * 256 = 133120
    int i = (blk - 512) * 256 + threadIdx.x;
    if (i >= 133120) return;
    int c = i & 255;
    int j = i >> 8;
    int b = (j >= 260) ? 1 : 0;
    int r = j - b * 260;
    int hp, wp;
    if (r < 66)       { hp = 0;        wp = r; }
    else if (r < 132) { hp = 65;       wp = r - 66; }
    else if (r < 196) { hp = r - 131;  wp = 0; }
    else              { hp = r - 195;  wp = 65; }
    xTb[(size_t)b * XT_BSTRIDE + (hp * 66 + wp) * 256 + c] = 0;
    return;
  }
  // prepack weights (bf16, B^T, swizzled); 991232 items
  int i = (blk - 1032) * 256 + threadIdx.x;
  if (i < 73728) {
    int o = i / 2304, k = i % 2304;
    int kp = k >> 8, c = k & 255;
    float v = 0.f;
    if (o < 18)      v = p_w[((size_t)o * 256 + c) * 9 + kp];
    else if (o < 27) v = m_w[((size_t)(o - 18) * 256 + c) * 9 + kp];
    W1t[swz_idx(o, k, 2304)] = f2bf(v);
    return;
  }
  int j = i - 73728;
  if (j < 589824) {
    int o = j / 2304, k = j % 2304;
    int n = k >> 8, c = k & 255;
    Wdt[swz_idx(o, k, 2304)] = f2bf(dconv_w[((size_t)o * 256 + c) * 9 + n]);
    return;
  }
  int j2 = j - 589824;
  if (j2 < 327680) {
    int o = j2 / 1280, k = j2 % 1280;
    int t = k >> 8, c = k & 255;
    const float* cw = cdc_w + ((size_t)o * 256 + c) * 5;
    float v = cw[t];
    if (t == 2) v -= THETA_ * (cw[0] + cw[1] + cw[2] + cw[3] + cw[4]);
    Wct[swz_idx(o, k, 1280)] = f2bf(v);
  }
}

// ---------------- sampling params (sums split-K partials, adds bias) --------
__global__ __launch_bounds__(256) void sample_params(
    const float* __restrict__ omp, const float* __restrict__ p_b,
    const float* __restrict__ m_b, int4* __restrict__ sidx,
    float4* __restrict__ sg) {
  int i = blockIdx.x * 256 + threadIdx.x;
  if (i >= 73728) return;
  int n = i % 9;
  int p = i / 9;
  int b = p >> 12;
  int hw = p & 4095;
  int h = hw >> 6, w = hw & 63;
  float offx = p_b[n], offy = p_b[9 + n], mraw = m_b[n];
#pragma unroll
  for (int ks = 0; ks < 4; ks++) {
    const float* base = omp + ks * 221184 + b * 110592;
    offx += base[(size_t)n * 4096 + hw];
    offy += base[(size_t)(9 + n) * 4096 + hw];
    mraw += base[(size_t)(18 + n) * 4096 + hw];
  }
  float px = offx + (float)(h + n / 3);
  float py = offy + (float)(w + n % 3);
  float fx = floorf(px), fy = floorf(py);
  float qx0 = fminf(fmaxf(fx, 0.f), 65.f);
  float qy0 = fminf(fmaxf(fy, 0.f), 65.f);
  float qx1 = fminf(fmaxf(fx + 1.f, 0.f), 65.f);
  float qy1 = fminf(fmaxf(fy + 1.f, 0.f), 65.f);
  float pxc = fminf(fmaxf(px, 0.f), 65.f);
  float pyc = fminf(fmaxf(py, 0.f), 65.f);
  float gx0 = 1.f + (qx0 - pxc);
  float gx1 = 1.f - (qx1 - pxc);
  float gy0 = 1.f + (qy0 - pyc);
  float gy1 = 1.f - (qy1 - pyc);
  float m = 1.f / (1.f + expf(-mraw));
  sidx[i] = make_int4((int)qx0 * 66 + (int)qy0, (int)qx1 * 66 + (int)qy1,
                      (int)qx0 * 66 + (int)qy1, (int)qx1 * 66 + (int)qy0);
  sg[i] = make_float4(gx0 * gy0 * m, gx1 * gy1 * m, gx0 * gy1 * m, gx1 * gy0 * m);
}

// ---------------- offmod partial GEMM (BM=128, BN=32, virtual 9-tap A) ------
__device__ __forceinline__ void offmod_body(
    const u16* __restrict__ xTb, const u16* __restrict__ Bt,
    float* __restrict__ outp, int mt, int kt0, int nkt, u16* As, u16* Bs) {
  int tid = threadIdx.x;
  int wid = tid >> 6, lane = tid & 63;
  int pbase = mt * 128;
  int l8 = lane >> 3, l7 = lane & 7;
  int lr = lane & 15, lg = lane >> 4;

  f32x4 acc[2][2];
#pragma unroll
  for (int i = 0; i < 2; i++)
#pragma unroll
    for (int j = 0; j < 2; j++) acc[i][j] = {0.f, 0.f, 0.f, 0.f};

  auto stage = [&](int kt, u16* Ah, u16* Bh) {
    int t = kt >> 2, c0 = (kt & 3) << 6;
    int dh = t / 3, dw = t % 3;
#pragma unroll
    for (int i = 0; i < 4; i++) {
      int r0 = wid * 32 + i * 8;
      int r = r0 + l8;
      int p = pbase + r;
      int b = p >> 12, hw = p & 4095, h = hw >> 6, w = hw & 63;
      int chunk = l7 ^ (r & 7);
      const u16* g = xTb + (size_t)b * XT_BSTRIDE +
                     ((h + dh) * 66 + (w + dw)) * 256 + c0 + (chunk << 3);
      GLOAD16(g, &Ah[r0 * 64]);
    }
    {
      int o0 = wid * 8;
      const u16* g = Bt + (size_t)(o0 + l8) * 2304 + kt * 64 + (l7 << 3);
      GLOAD16(g, &Bh[o0 * 64]);
    }
  };

  stage(kt0, As, Bs);
  __syncthreads();

  for (int it = 0; it < nkt; it++) {
    int cur = it & 1;
    u16* Ac = As + cur * (128 * 64);
    u16* Bc = Bs + cur * (32 * 64);
    if (it + 1 < nkt)
      stage(kt0 + it + 1, As + (cur ^ 1) * (128 * 64), Bs + (cur ^ 1) * (32 * 64));

    bf16x8 av[2][2], bv[2][2];
#pragma unroll
    for (int mf = 0; mf < 2; mf++) {
      int r = wid * 32 + mf * 16 + lr;
#pragma unroll
      for (int ks = 0; ks < 2; ks++) {
        int kc = ks * 4 + lg;
        av[mf][ks] = *(const bf16x8*)&Ac[r * 64 + ((kc ^ (r & 7)) << 3)];
      }
    }
#pragma unroll
    for (int nf = 0; nf < 2; nf++) {
      int o = nf * 16 + lr;
#pragma unroll
      for (int ks = 0; ks < 2; ks++) {
        int kc = ks * 4 + lg;
        bv[nf][ks] = *(const bf16x8*)&Bc[o * 64 + ((kc ^ (o & 7)) << 3)];
      }
    }
#pragma unroll
    for (int nf = 0; nf < 2; nf++)
#pragma unroll
      for (int mf = 0; mf < 2; mf++)
#pragma unroll
        for (int ks = 0; ks < 2; ks++)
          acc[nf][mf] = __builtin_amdgcn_mfma_f32_16x16x32_bf16(
              bv[nf][ks], av[mf][ks], acc[nf][mf], 0, 0, 0);
    __syncthreads();
  }

#pragma unroll
  for (int nf = 0; nf < 2; nf++)
#pragma unroll
    for (int mf = 0; mf < 2; mf++) {
      int p = pbase + wid * 32 + mf * 16 + lr;
      int hw = p & 4095, b = p >> 12;
      int o0 = nf * 16 + lg * 4;
      f32x4 v = acc[nf][mf];
#pragma unroll
      for (int e = 0; e < 4; e++) {
        int o = o0 + e;
        if (o < 27)
          outp[(size_t)(b * 27 + o) * 4096 + hw] = v[e];
      }
    }
}

__global__ __launch_bounds__(256) void gemm_offmod(const u16* __restrict__ xTb,
                                                   const u16* __restrict__ W1t,
                                                   float* __restrict__ omp) {
  __shared__ u16 As[2 * 128 * 64];
  __shared__ u16 Bs[2 * 32 * 64];
  int bid = blockIdx.x;
  int xcd = bid & 7;
  int i = bid >> 3;                 // 0..31
  int mt = xcd * 8 + (i & 7);
  int ks = i >> 3;                  // 0..3
  offmod_body(xTb, W1t, omp + ks * 221184, mt, ks * 9, 9, As, Bs);
}

// ---------------- fused deform GEMM (BM=32, BN=256, full T14 pipeline) ------
// Both A (bilinear gather) and B (weights) are REGISTER-staged: loads for
// tile it+1 issued before the MFMA of tile it; convert + ds_write after the
// MFMA (sched_barrier pins the order). The end-of-iter __syncthreads then has
// no outstanding VMEM to drain — loads always overlap compute.
// LDS (u16): A halves [0,2048),[2048,4096); B halves [4096,20480),[20480,36864)
__device__ void deform_body(const u16* __restrict__ xTb,
                            const u16* __restrict__ Wdt,
                            const int4* __restrict__ sidx,
                            const float4* __restrict__ sg,
                            float* __restrict__ out, int mt, u16* S) {
  const int NKT = 36;
  int tid = threadIdx.x;
  int wid = tid >> 6, lane = tid & 63;
  int l8 = lane >> 3, l7 = lane & 7;
  int lr = lane & 15, lg = lane >> 4;
  int pbase = mt * 32;
  int b = pbase >> 12;
  const u16* xb = xTb + (size_t)b * XT_BSTRIDE;

  // gather assignment: row gr = tid>>3 (0..31), chunk kc = tid&7
  int gr = tid >> 3;
  int gp = pbase + gr;
  int kc = tid & 7;

  f32x4 acc[4][2];  // [nf][mf]
#pragma unroll
  for (int i = 0; i < 4; i++)
#pragma unroll
    for (int j = 0; j < 2; j++) acc[i][j] = {0.f, 0.f, 0.f, 0.f};

  u16* A0 = S;
  u16* B0 = S + 4096;

  // tap-state registers (tap = kt>>2); next-tap prefetched 4 iters early
  int4 qi = sidx[gp * 9 + 0];
  float4 g = sg[gp * 9 + 0];
  int4 qi_n = sidx[gp * 9 + 1];
  float4 g_n = sg[gp * 9 + 1];

  bf16x8 c0r, c1r, c2r, c3r;   // in-flight corner loads (A)
  float4 gc;
  bf16x8 br[8];                // in-flight B loads

  auto issueA = [&](int kt) {
    int c0 = (kt & 3) << 6;
    const u16* xc = xb + c0 + (kc << 3);
    c0r = *(const bf16x8*)(xc + (size_t)qi.x * 256);
    c1r = *(const bf16x8*)(xc + (size_t)qi.y * 256);
    c2r = *(const bf16x8*)(xc + (size_t)qi.z * 256);
    c3r = *(const bf16x8*)(xc + (size_t)qi.w * 256);
    gc = g;
  };
  auto issueB = [&](int kt) {
#pragma unroll
    for (int i = 0; i < 8; i++) {
      int o0 = wid * 64 + i * 8;
      br[i] = *(const bf16x8*)(Wdt + (size_t)(o0 + l8) * 2304 + kt * 64 + (l7 << 3));
    }
  };
  auto writeA = [&](u16* Ah) {
    bf16x8 p;
#pragma unroll
    for (int j = 0; j < 8; j++) {
      float v = gc.x * bf2f((u16)c0r[j]) + gc.y * bf2f((u16)c1r[j]) +
                gc.z * bf2f((u16)c2r[j]) + gc.w * bf2f((u16)c3r[j]);
      p[j] = (short)f2bf(v);
    }
    *(bf16x8*)&Ah[gr * 64 + ((kc ^ (gr & 7)) << 3)] = p;
  };
  auto writeB = [&](u16* Bh) {
#pragma unroll
    for (int i = 0; i < 8; i++) {
      int o0 = wid * 64 + i * 8;
      *(bf16x8*)&Bh[(o0 + l8) * 64 + (l7 << 3)] = br[i];
    }
  };

  // prologue: tile 0
  issueA(0);
  issueB(0);
  writeA(A0);
  writeB(B0);
  __syncthreads();

  for (int it = 0; it < NKT; it++) {
    int cur = it & 1;
    u16* Ac = A0 + cur * 2048;
    u16* Bc = B0 + cur * 16384;

    if (it + 1 < NKT) {
      if (((it + 1) & 3) == 0) {       // next tile starts a new tap
        qi = qi_n; g = g_n;
        int tapn = ((it + 1) >> 2) + 1;
        if (tapn < 9) { qi_n = sidx[gp * 9 + tapn]; g_n = sg[gp * 9 + tapn]; }
      }
      issueA(it + 1);                  // VMEM issue only — drains under MFMA
      issueB(it + 1);
    }

    bf16x8 av[2][2], bv[4][2];
#pragma unroll
    for (int mf = 0; mf < 2; mf++) {
      int r = mf * 16 + lr;
#pragma unroll
      for (int ks = 0; ks < 2; ks++) {
        int kk = ks * 4 + lg;
        av[mf][ks] = *(const bf16x8*)&Ac[r * 64 + ((kk ^ (r & 7)) << 3)];
      }
    }
#pragma unroll
    for (int nf = 0; nf < 4; nf++) {
      int o = wid * 64 + nf * 16 + lr;
#pragma unroll
      for (int ks = 0; ks < 2; ks++) {
        int kk = ks * 4 + lg;
        bv[nf][ks] = *(const bf16x8*)&Bc[o * 64 + ((kk ^ (o & 7)) << 3)];
      }
    }
    __builtin_amdgcn_s_setprio(1);
#pragma unroll
    for (int nf = 0; nf < 4; nf++)
#pragma unroll
      for (int mf = 0; mf < 2; mf++)
#pragma unroll
        for (int ks = 0; ks < 2; ks++)
          acc[nf][mf] = __builtin_amdgcn_mfma_f32_16x16x32_bf16(
              bv[nf][ks], av[mf][ks], acc[nf][mf], 0, 0, 0);
    __builtin_amdgcn_s_setprio(0);
    __builtin_amdgcn_sched_barrier(0);  // keep the stores below the MFMAs

    if (it + 1 < NKT) {
      writeA(A0 + (cur ^ 1) * 2048);   // waits corner loads; done under MFMA
      writeB(B0 + (cur ^ 1) * 16384);  // waits B loads; done under MFMA
    }
    __syncthreads();                   // nothing left outstanding to drain
  }

  // epilogue: ReLU, out ch 0..255
#pragma unroll
  for (int nf = 0; nf < 4; nf++)
#pragma unroll
    for (int mf = 0; mf < 2; mf++) {
      int p = pbase + mf * 16 + lr;
      int hw = p & 4095;
      int og = wid * 64 + nf * 16 + lg * 4;
      f32x4 v = acc[nf][mf];
#pragma unroll
      for (int e = 0; e < 4; e++)
        out[(size_t)(b * 512 + og + e) * 4096 + hw] = fmaxf(v[e], 0.f);
    }
}

// ---------------- cdc GEMM (BM=64, BN=64, virtual 5-tap A) ------------------
// LDS in S: A halves [0,4096),[4096,8192); B halves [8192,12288),[12288,16384)
__device__ void cdc_body(const u16* __restrict__ xTb,
                         const u16* __restrict__ Wct,
                         float* __restrict__ out, int mt, int nt, u16* S) {
  const int NKT = 20;
  int tid = threadIdx.x;
  int wid = tid >> 6, lane = tid & 63;
  int wr = wid >> 1, wc = wid & 1;
  int l8 = lane >> 3, l7 = lane & 7;
  int lr = lane & 15, lg = lane >> 4;
  int pbase = mt * 64;
  int obase = nt * 64;
  int b = pbase >> 12;

  f32x4 acc[2][2];
#pragma unroll
  for (int i = 0; i < 2; i++)
#pragma unroll
    for (int j = 0; j < 2; j++) acc[i][j] = {0.f, 0.f, 0.f, 0.f};

  const int dh1[5] = {0, 1, 1, 1, 2}, dw1[5] = {1, 0, 1, 2, 1};
  u16* A0 = S;
  u16* B0 = S + 8192;

  auto stage = [&](int kt, u16* Ah, u16* Bh) {
    int t = kt >> 2, c0 = (kt & 3) << 6;
    int dh = dh1[t], dw = dw1[t];
#pragma unroll
    for (int i = 0; i < 2; i++) {
      int r0 = wid * 16 + i * 8;
      int r = r0 + l8;
      int p = pbase + r;
      int hw = p & 4095, h = hw >> 6, w = hw & 63;
      int chunk = l7 ^ (r & 7);
      const u16* g = xTb + (size_t)b * XT_BSTRIDE +
                     ((h + dh) * 66 + (w + dw)) * 256 + c0 + (chunk << 3);
      GLOAD16(g, &Ah[r0 * 64]);
    }
#pragma unroll
    for (int i = 0; i < 2; i++) {
      int o0 = wid * 16 + i * 8;
      const u16* g = Wct + (size_t)(obase + o0 + l8) * 1280 + kt * 64 + (l7 << 3);
      GLOAD16(g, &Bh[o0 * 64]);
    }
  };

  stage(0, A0, B0);
  __syncthreads();

  for (int it = 0; it < NKT; it++) {
    int cur = it & 1;
    u16* Ac = A0 + cur * 4096;
    u16* Bc = B0 + cur * 4096;
    if (it + 1 < NKT)
      stage(it + 1, A0 + (cur ^ 1) * 4096, B0 + (cur ^ 1) * 4096);

    bf16x8 av[2][2], bv[2][2];
#pragma unroll
    for (int mf = 0; mf < 2; mf++) {
      int r = wr * 32 + mf * 16 + lr;
#pragma unroll
      for (int ks = 0; ks < 2; ks++) {
        int kk = ks * 4 + lg;
        av[mf][ks] = *(const bf16x8*)&Ac[r * 64 + ((kk ^ (r & 7)) << 3)];
      }
    }
#pragma unroll
    for (int nf = 0; nf < 2; nf++) {
      int o = wc * 32 + nf * 16 + lr;
#pragma unroll
      for (int ks = 0; ks < 2; ks++) {
        int kk = ks * 4 + lg;
        bv[nf][ks] = *(const bf16x8*)&Bc[o * 64 + ((kk ^ (o & 7)) << 3)];
      }
    }
#pragma unroll
    for (int nf = 0; nf < 2; nf++)
#pragma unroll
      for (int mf = 0; mf < 2; mf++)
#pragma unroll
        for (int ks = 0; ks < 2; ks++)
          acc[nf][mf] = __builtin_amdgcn_mfma_f32_16x16x32_bf16(
              bv[nf][ks], av[mf][ks], acc[nf][mf], 0, 0, 0);
    __syncthreads();
  }

#pragma unroll
  for (int nf = 0; nf < 2; nf++)
#pragma unroll
    for (int mf = 0; mf < 2; mf++) {
      int p = pbase + wr * 32 + mf * 16 + lr;
      int hw = p & 4095;
      int og = 256 + obase + wc * 32 + nf * 16 + lg * 4;
      f32x4 v = acc[nf][mf];
#pragma unroll
      for (int e = 0; e < 4; e++)
        out[(size_t)(b * 512 + og + e) * 4096 + hw] = fmaxf(v[e], 0.f);
    }
}

// ---------------- main GEMM: 256 fused-deform blocks + 512 cdc blocks -------
__global__ __launch_bounds__(256, 2) void gemm_main(
    const u16* __restrict__ xTb, const u16* __restrict__ Wdt,
    const u16* __restrict__ Wct, const int4* __restrict__ sidx,
    const float4* __restrict__ sg, float* __restrict__ out) {
  __shared__ u16 S[36864];   // 72 KiB -> 2 blocks/CU
  int bid = blockIdx.x;
  if (bid < 256) {
    // deform: XCD-chunked, 32 consecutive mt per XCD
    int mt = (bid & 7) * 32 + (bid >> 3);
    deform_body(xTb, Wdt, sidx, sg, out, mt, S);
  } else {
    int i = bid - 256;               // 0..511
    int xcd = i & 7;
    int j = i >> 3;                  // 0..63
    int mt = xcd * 16 + (j & 15);
    int nt = j >> 4;                 // 0..3
    cdc_body(xTb, Wct, out, mt, nt, S);
  }
}

// ---------------- launch ----------------------------------------------------
extern "C" void kernel_launch(void* const* d_in, const int* in_sizes, int n_in,
                              void* d_out, int out_size, void* d_ws, size_t ws_size,
                              hipStream_t stream) {
  (void)in_sizes; (void)n_in; (void)out_size; (void)ws_size;
  const float* x       = (const float*)d_in[0];
  const float* p_w     = (const float*)d_in[1];
  const float* p_b     = (const float*)d_in[2];
  const float* m_w     = (const float*)d_in[3];
  const float* m_b     = (const float*)d_in[4];
  const float* dconv_w = (const float*)d_in[5];
  const float* cdc_w   = (const float*)d_in[6];
  float* out = (float*)d_out;
  char* ws = (char*)d_ws;

  u16*   xTb  = (u16*)(ws);                   // 4,460,544 B
  float* omp  = (float*)(ws + 4460544);       // 3,538,944 B (4 K-slices)
  u16*   W1t  = (u16*)(ws + 7999488);         //   147,456 B
  u16*   Wdt  = (u16*)(ws + 8146944);         // 1,179,648 B
  u16*   Wct  = (u16*)(ws + 9326592);         //   655,360 B
  int4*  sidx = (int4*)(ws + 9981952);        // 1,179,648 B
  float4* sg  = (float4*)(ws + 11161600);     // 1,179,648 B (end 12,341,248)

  prep<<<4904, 256, 0, stream>>>(x, p_w, m_w, dconv_w, cdc_w, xTb, W1t, Wdt, Wct);
  gemm_offmod<<<256, 256, 0, stream>>>(xTb, W1t, omp);
  sample_params<<<288, 256, 0, stream>>>(omp, p_b, m_b, sidx, sg);
  gemm_main<<<768, 256, 0, stream>>>(xTb, Wdt, Wct, sidx, sg, out);
}